// Round 1
// baseline (2639.791 us; speedup 1.0000x reference)
//
#include <hip/hip_runtime.h>
#include <hip/hip_bf16.h>
#include <cstdint>

#define B_   2048
#define H_   512
#define T_   128
#define V_   64
#define FOURH 2048

typedef __bf16 bf16x8 __attribute__((ext_vector_type(8)));
typedef float  floatx4 __attribute__((ext_vector_type(4)));

__device__ __forceinline__ unsigned short f2bf(float f) {
    union { float f; uint32_t u; } v; v.f = f;
    uint32_t r = v.u + 0x7fff + ((v.u >> 16) & 1);
    return (unsigned short)(r >> 16);
}

__device__ __forceinline__ float sigmoidf_(float x) {
    return 1.0f / (1.0f + __expf(-x));
}
__device__ __forceinline__ float tanhf_(float x) {
    float e = __expf(fminf(-2.0f * x, 80.0f));
    return (1.0f - e) / (1.0f + e);
}

__device__ __forceinline__ void global_to_lds16(const unsigned short* g, unsigned short* l) {
    __builtin_amdgcn_global_load_lds(
        (const __attribute__((address_space(1))) unsigned int*)g,
        (__attribute__((address_space(3))) unsigned int*)l, 16, 0, 0);
}

// ---------------------------------------------------------------------------
// prep: build permuted bf16 weights, bf16 z, bf16 fc_w, fused permuted bias.
// Permutation: col' = j*128 + gate*32 + hcl  <->  p = gate*512 + j*32 + hcl
// ---------------------------------------------------------------------------
__global__ void prep_kernel(const float* __restrict__ z,
                            const float* __restrict__ w_ih,
                            const float* __restrict__ w_hh,
                            const float* __restrict__ b_ih,
                            const float* __restrict__ b_hh,
                            const float* __restrict__ fc_w,
                            unsigned short* __restrict__ Bp_ih,
                            unsigned short* __restrict__ Bp_hh,
                            unsigned short* __restrict__ z_bf,
                            unsigned short* __restrict__ fcw_bf,
                            float* __restrict__ biasp) {
    int i = blockIdx.x * blockDim.x + threadIdx.x;   // exactly 2048*512 threads
    int col = i >> 9, k = i & 511;
    int jj = col >> 7, wn = col & 127;
    int p = (wn >> 5) * 512 + jj * 32 + (wn & 31);
    Bp_hh[i] = f2bf(w_hh[p * 512 + k]);
    Bp_ih[i] = f2bf(w_ih[p * 512 + k]);
    z_bf[i]  = f2bf(z[i]);
    if (i < V_ * H_) fcw_bf[i] = f2bf(fc_w[i]);
    if (i < FOURH) {
        int j2 = i >> 7, w2 = i & 127;
        int p2 = (w2 >> 5) * 512 + j2 * 32 + (w2 & 31);
        biasp[i] = b_ih[p2] + b_hh[p2];
    }
}

// ---------------------------------------------------------------------------
// Shared 128x128 (K=512, BK=64) MFMA tile core.
// A = [128 rows][512] bf16 row-major (rows arow0..+128), B = [128 cols][512].
// LDS layout: [row][8 granules of 16B], granule slot = logical_g ^ (row&7).
// Wave w computes rows 32w..32w+32 x all 128 cols -> acc[2][8] (float4).
// ---------------------------------------------------------------------------
__device__ __forceinline__ void gemm_tile_128x128(
        const unsigned short* __restrict__ Aglob,
        const unsigned short* __restrict__ Bglob,
        int arow0, int brow0,
        unsigned short* As, unsigned short* Bs,
        floatx4 acc[2][8], int w, int l) {
    const int lr = l >> 3;            // row within 8-row staging group
    const int gl = (l & 7) ^ lr;      // swizzled source granule
    const int ln = l & 15, lq = l >> 4, ls = l & 7;
    for (int kc = 0; kc < 8; ++kc) {
        const int kof = kc * 64 + gl * 8;
        #pragma unroll
        for (int q = 0; q < 4; ++q) {
            const int r0 = (w * 4 + q) * 8;
            global_to_lds16(Aglob + (arow0 + r0 + lr) * 512 + kof, As + r0 * 64);
            global_to_lds16(Bglob + (brow0 + r0 + lr) * 512 + kof, Bs + r0 * 64);
        }
        __syncthreads();
        #pragma unroll
        for (int kk = 0; kk < 2; ++kk) {
            bf16x8 a[2], b[8];
            #pragma unroll
            for (int mt = 0; mt < 2; ++mt) {
                const int m = 32 * w + 16 * mt + ln;
                const int g = kk * 4 + lq;
                a[mt] = *(const bf16x8*)(As + m * 64 + ((g ^ ls) * 8));
            }
            #pragma unroll
            for (int nt = 0; nt < 8; ++nt) {
                const int n = 16 * nt + ln;
                const int g = kk * 4 + lq;
                b[nt] = *(const bf16x8*)(Bs + n * 64 + ((g ^ ls) * 8));
            }
            #pragma unroll
            for (int mt = 0; mt < 2; ++mt)
                #pragma unroll
                for (int nt = 0; nt < 8; ++nt)
                    acc[mt][nt] = __builtin_amdgcn_mfma_f32_16x16x32_bf16(
                        a[mt], b[nt], acc[mt][nt], 0, 0, 0);
        }
        __syncthreads();
    }
}

// 16-row x 64-col projection of h rows [pr0, pr0+16) -> out[:, tslot, :]
__device__ __forceinline__ void proj16(const unsigned short* __restrict__ h,
                                       const unsigned short* __restrict__ fcw_bf,
                                       const float* __restrict__ fc_b,
                                       float* __restrict__ out,
                                       int pr0, int tslot, int w, int l) {
    const int ln = l & 15, lq = l >> 4;
    floatx4 pacc = {0.f, 0.f, 0.f, 0.f};
    const int arow = pr0 + ln;
    const int v = 16 * w + ln;             // wave w owns v-cols 16w..16w+16
    #pragma unroll
    for (int kc = 0; kc < 16; ++kc) {
        const int k = kc * 32 + lq * 8;
        bf16x8 a = *(const bf16x8*)(h + arow * 512 + k);
        bf16x8 b = *(const bf16x8*)(fcw_bf + v * 512 + k);
        pacc = __builtin_amdgcn_mfma_f32_16x16x32_bf16(a, b, pacc, 0, 0, 0);
    }
    const float bias = fc_b[v];
    #pragma unroll
    for (int r = 0; r < 4; ++r) {
        const int b = pr0 + lq * 4 + r;
        out[b * (T_ * V_) + tslot * V_ + v] = fmaxf(pacc[r] + bias, 0.0f);
    }
}

// ---------------------------------------------------------------------------
// Prologue GEMM: xg' = z_bf @ Bp_ih (permuted cols) + biasp, fp32 out.
// ---------------------------------------------------------------------------
__global__ void __launch_bounds__(256) xg_gemm_kernel(
        const unsigned short* __restrict__ z_bf,
        const unsigned short* __restrict__ Bp_ih,
        const float* __restrict__ biasp,
        float* __restrict__ xg) {
    __shared__ unsigned short As[128 * 64];
    __shared__ unsigned short Bs[128 * 64];
    const int bi = blockIdx.x, j = blockIdx.y;
    const int tid = threadIdx.x, w = tid >> 6, l = tid & 63;
    floatx4 acc[2][8];
    const floatx4 zf = {0.f, 0.f, 0.f, 0.f};
    for (int a1 = 0; a1 < 2; ++a1) for (int a2 = 0; a2 < 8; ++a2) acc[a1][a2] = zf;

    gemm_tile_128x128(z_bf, Bp_ih, bi * 128, j * 128, As, Bs, acc, w, l);

    const int ln = l & 15, lq = l >> 4;
    #pragma unroll
    for (int mt = 0; mt < 2; ++mt)
        #pragma unroll
        for (int nt = 0; nt < 8; ++nt) {
            const int colp = j * 128 + nt * 16 + ln;
            const float bv = biasp[colp];
            #pragma unroll
            for (int r = 0; r < 4; ++r) {
                const int b = bi * 128 + 32 * w + 16 * mt + lq * 4 + r;
                xg[b * FOURH + colp] = acc[mt][nt][r] + bv;
            }
        }
}

// ---------------------------------------------------------------------------
// t = 0: gates == xg (h=0, c=0) -> pure elementwise.
// ---------------------------------------------------------------------------
__global__ void t0_kernel(const float* __restrict__ xg,
                          float* __restrict__ c_st,
                          unsigned short* __restrict__ h0) {
    int i = blockIdx.x * blockDim.x + threadIdx.x;  // exactly 2048*512
    int b = i >> 9, hc = i & 511;
    int j = hc >> 5, hcl = hc & 31;
    const float* xr = xg + b * FOURH + j * 128;
    float xi = xr[hcl], xgv = xr[64 + hcl], xo = xr[96 + hcl];
    float cv = sigmoidf_(xi) * tanhf_(xgv);   // f*c0 term vanishes (c0 = 0)
    float hv = sigmoidf_(xo) * tanhf_(cv);
    c_st[i] = cv;
    h0[i]   = f2bf(hv);
}

// ---------------------------------------------------------------------------
// One recurrent step t (t >= 1):
//   gates = xg + h_prev @ Bp_hh^T  (permuted cols) -> cell update -> h_next
//   plus (j<8): projection of h_prev -> out[:, t-1, :]
// ---------------------------------------------------------------------------
__global__ void __launch_bounds__(256) step_kernel(
        const unsigned short* __restrict__ h_prev,
        unsigned short* __restrict__ h_next,
        const unsigned short* __restrict__ Bp_hh,
        const float* __restrict__ xg,
        float* __restrict__ c_st,
        const unsigned short* __restrict__ fcw_bf,
        const float* __restrict__ fc_b,
        float* __restrict__ out,
        int t) {
    __shared__ unsigned short As[128 * 64];
    __shared__ unsigned short Bs[128 * 64];
    const int bi = blockIdx.x, j = blockIdx.y;
    const int tid = threadIdx.x, w = tid >> 6, l = tid & 63;
    floatx4 acc[2][8];
    const floatx4 zf = {0.f, 0.f, 0.f, 0.f};
    for (int a1 = 0; a1 < 2; ++a1) for (int a2 = 0; a2 < 8; ++a2) acc[a1][a2] = zf;

    gemm_tile_128x128(h_prev, Bp_hh, bi * 128, j * 128, As, Bs, acc, w, l);

    // cell update epilogue: tile cols = [i(32)|f(32)|g(32)|o(32)] for hcl 0..31
    const int ln = l & 15, lq = l >> 4;
    #pragma unroll
    for (int mt = 0; mt < 2; ++mt) {
        #pragma unroll
        for (int nh = 0; nh < 2; ++nh) {
            const floatx4 ai = acc[mt][0 + nh];
            const floatx4 af = acc[mt][2 + nh];
            const floatx4 ag = acc[mt][4 + nh];
            const floatx4 ao = acc[mt][6 + nh];
            const int hcl = nh * 16 + ln;       // 0..31
            const int hc  = j * 32 + hcl;       // 0..511
            #pragma unroll
            for (int r = 0; r < 4; ++r) {
                const int b = bi * 128 + 32 * w + 16 * mt + lq * 4 + r;
                const float* xr = xg + b * FOURH + j * 128;
                float iv = sigmoidf_(ai[r] + xr[hcl]);
                float fv = sigmoidf_(af[r] + xr[32 + hcl]);
                float gv = tanhf_  (ag[r] + xr[64 + hcl]);
                float ov = sigmoidf_(ao[r] + xr[96 + hcl]);
                float cn = fv * c_st[b * 512 + hc] + iv * gv;
                c_st[b * 512 + hc]  = cn;
                h_next[b * 512 + hc] = f2bf(ov * tanhf_(cn));
            }
        }
    }

    // off-critical-path projection of h_prev -> out[:, t-1, :]
    if (j < 8) {
        proj16(h_prev, fcw_bf, fc_b, out, bi * 128 + j * 16, t - 1, w, l);
    }
}

__global__ void __launch_bounds__(256) final_proj_kernel(
        const unsigned short* __restrict__ h,
        const unsigned short* __restrict__ fcw_bf,
        const float* __restrict__ fc_b,
        float* __restrict__ out) {
    proj16(h, fcw_bf, fc_b, out,
           blockIdx.x * 128 + blockIdx.y * 16, T_ - 1,
           threadIdx.x >> 6, threadIdx.x & 63);
}

// ---------------------------------------------------------------------------
extern "C" void kernel_launch(void* const* d_in, const int* in_sizes, int n_in,
                              void* d_out, int out_size, void* d_ws, size_t ws_size,
                              hipStream_t stream) {
    const float* z    = (const float*)d_in[0];
    const float* w_ih = (const float*)d_in[1];
    const float* w_hh = (const float*)d_in[2];
    const float* b_ih = (const float*)d_in[3];
    const float* b_hh = (const float*)d_in[4];
    const float* fc_w = (const float*)d_in[5];
    const float* fc_b = (const float*)d_in[6];
    float* out = (float*)d_out;

    char* ws = (char*)d_ws;
    size_t o = 0;
    auto take = [&](size_t bytes) { char* p = ws + o; o += (bytes + 255) & ~(size_t)255; return p; };
    unsigned short* Bp_hh  = (unsigned short*)take((size_t)FOURH * H_ * 2);  // 2 MB
    unsigned short* Bp_ih  = (unsigned short*)take((size_t)FOURH * H_ * 2);  // 2 MB
    unsigned short* z_bf   = (unsigned short*)take((size_t)B_ * H_ * 2);     // 2 MB
    unsigned short* fcw_bf = (unsigned short*)take((size_t)V_ * H_ * 2);     // 64 KB
    float*          biasp  = (float*)take((size_t)FOURH * 4);                // 8 KB
    float*          c_st   = (float*)take((size_t)B_ * H_ * 4);              // 4 MB
    unsigned short* hbuf0  = (unsigned short*)take((size_t)B_ * H_ * 2);     // 2 MB
    unsigned short* hbuf1  = (unsigned short*)take((size_t)B_ * H_ * 2);     // 2 MB
    float*          xg     = (float*)take((size_t)B_ * FOURH * 4);           // 16 MB

    unsigned short* hb[2] = {hbuf0, hbuf1};

    prep_kernel<<<(B_ * H_) / 256, 256, 0, stream>>>(z, w_ih, w_hh, b_ih, b_hh, fc_w,
                                                     Bp_ih, Bp_hh, z_bf, fcw_bf, biasp);
    xg_gemm_kernel<<<dim3(16, 16), 256, 0, stream>>>(z_bf, Bp_ih, biasp, xg);
    t0_kernel<<<(B_ * H_) / 256, 256, 0, stream>>>(xg, c_st, hb[0]);
    for (int t = 1; t < T_; ++t) {
        step_kernel<<<dim3(16, 16), 256, 0, stream>>>(
            hb[(t - 1) & 1], hb[t & 1], Bp_hh, xg, c_st, fcw_bf, fc_b, out, t);
    }
    final_proj_kernel<<<dim3(16, 8), 256, 0, stream>>>(hb[(T_ - 1) & 1], fcw_bf, fc_b, out);
}